// Round 9
// baseline (664.066 us; speedup 1.0000x reference)
//
#include <hip/hip_runtime.h>

#define D_FEAT 128
typedef unsigned int u32;
typedef unsigned long long u64;
typedef u32   u32x4 __attribute__((ext_vector_type(4)));
typedef float f32x4 __attribute__((ext_vector_type(4)));

__device__ __forceinline__ float bflo(u32 w) {
    u32 b = w << 16;
    return __builtin_bit_cast(float, b);
}
__device__ __forceinline__ float bfhi(u32 w) {
    u32 b = w & 0xFFFF0000u;
    return __builtin_bit_cast(float, b);
}
__device__ __forceinline__ u32 f2bf(float f) {
    u32 x = __builtin_bit_cast(u32, f);
    return (x + 0x7FFFu + ((x >> 16) & 1u)) >> 16;
}
__device__ __forceinline__ u32 pack2(float lo, float hi) {
    return f2bf(lo) | (f2bf(hi) << 16);
}

// ---------------- CSR build helpers ----------------

__global__ void hist_keys(const int* __restrict__ key, int* __restrict__ deg, int n) {
    int e = blockIdx.x * blockDim.x + threadIdx.x;
    if (e < n) atomicAdd(&deg[__builtin_nontemporal_load(&key[e])], 1);
}

__global__ void scan_blocks(const int* __restrict__ deg, int* __restrict__ ptrOut,
                            int* __restrict__ bsum, int n) {
    __shared__ int s[256];
    int t = threadIdx.x;
    int i = blockIdx.x * 256 + t;
    int v = (i < n) ? deg[i] : 0;
    s[t] = v;
    __syncthreads();
    for (int off = 1; off < 256; off <<= 1) {
        int add = (t >= off) ? s[t - off] : 0;
        __syncthreads();
        s[t] += add;
        __syncthreads();
    }
    if (i < n) ptrOut[i] = s[t] - v;
    if (t == 255) bsum[blockIdx.x] = s[255];
}

__global__ void scan_bsums(int* __restrict__ bsum, int nb) {
    __shared__ int s[1024];
    int t = threadIdx.x;
    int v = (t < nb) ? bsum[t] : 0;
    s[t] = v;
    __syncthreads();
    for (int off = 1; off < 1024; off <<= 1) {
        int add = (t >= off) ? s[t - off] : 0;
        __syncthreads();
        s[t] += add;
        __syncthreads();
    }
    if (t < nb) bsum[t] = s[t] - v;
}

__global__ void add_offsets(int* __restrict__ ptr, int* __restrict__ next,
                            const int* __restrict__ bsum, int n, int total) {
    int i = blockIdx.x * blockDim.x + threadIdx.x;
    if (i < n) {
        int p = ptr[i] + bsum[i >> 8];
        ptr[i] = p;
        next[i] = p;
    }
    if (i == n) ptr[n] = total;
}

// ---- Phase A: ballot-aggregated partition into 8 staged buckets + deg hist ----
// 4096 edges/block (16/thread). Per-wave per-bucket rank via __ballot/popcll
// (no LDS scans, no per-edge placement atomics). 8 global atomics per block.
__global__ void partition_ballot(const int* __restrict__ row, const int* __restrict__ col,
                                 int* __restrict__ deg, u32* __restrict__ cursor,
                                 u32* __restrict__ stag, int nE, int W,
                                 u64 M, int cbits, int capB) {
    __shared__ u32 wcnt[4][8];
    __shared__ u32 gwb[4][8];
    int t = threadIdx.x;
    int wv = t >> 6;
    int lane = t & 63;
    u64 ltmask = (1ull << lane) - 1;
    long long base = (long long)blockIdx.x * 4096;

    u32 cnt[8];
#pragma unroll
    for (int b = 0; b < 8; ++b) cnt[b] = 0;

    int bkt[16];
    int rk[16];
    u32 pk[16];

#pragma unroll
    for (int k = 0; k < 16; ++k) {
        long long e = base + k * 256 + t;
        bool val = e < nE;
        int r = 0, c = 0;
        if (val) {
            r = __builtin_nontemporal_load(&row[e]);
            c = __builtin_nontemporal_load(&col[e]);
            atomicAdd(&deg[r], 1);
        }
        int b = val ? (int)(((u64)(u32)r * M) >> 40) : 8;
        bkt[k] = b;
        pk[k] = ((u32)(r - b * W) << cbits) | (u32)c;
#pragma unroll
        for (int bb = 0; bb < 8; ++bb) {
            u64 m = __ballot(b == bb);
            if (b == bb) rk[k] = (int)(cnt[bb] + (u32)__popcll(m & ltmask));
            cnt[bb] += (u32)__popcll(m);
        }
    }

    if (lane == 0) {
#pragma unroll
        for (int b = 0; b < 8; ++b) wcnt[wv][b] = cnt[b];
    }
    __syncthreads();
    if (t < 8) {
        u32 c0 = wcnt[0][t], c1 = wcnt[1][t], c2 = wcnt[2][t], c3 = wcnt[3][t];
        u32 gb = atomicAdd(&cursor[t], c0 + c1 + c2 + c3);
        gwb[0][t] = gb;
        gwb[1][t] = gb + c0;
        gwb[2][t] = gb + c0 + c1;
        gwb[3][t] = gb + c0 + c1 + c2;
    }
    __syncthreads();

#pragma unroll
    for (int k = 0; k < 16; ++k) {
        int b = bkt[k];
        if (b < 8) {
            u32 dst = gwb[wv][b] + (u32)rk[k];
            if (dst < (u32)capB)
                __builtin_nontemporal_store(pk[k], &stag[(size_t)b * capB + dst]);
        }
    }
}

// ---- Phase B: per-bucket atomic placement into its colS window (XCD affinity) ----
__global__ void scatter_staged(const u32* __restrict__ cursor, const u32* __restrict__ stag,
                               int* __restrict__ next, int* __restrict__ colS,
                               int W, int cbits, int capB) {
    int b = blockIdx.x & 7;
    int nchunk = gridDim.x >> 3;
    int chunk = blockIdx.x >> 3;
    int cnt = (int)cursor[b];
    if (cnt > capB) cnt = capB;
    int lo = b * W;
    u32 cmask = (1u << cbits) - 1;
    const u32* sb = stag + (size_t)b * capB;
    for (int i = chunk * 256 + threadIdx.x; i < cnt; i += nchunk * 256) {
        u32 w = __builtin_nontemporal_load(&sb[i]);
        int r = lo + (int)(w >> cbits);
        int c = (int)(w & cmask);
        int pos = atomicAdd(&next[r], 1);
        colS[pos] = c;
    }
}

// ---- fallback one-pass bucketed scatter (plain store) ----
#define EPB 2048
__global__ void scatter_cols_b(const int* __restrict__ row, const int* __restrict__ col,
                               int* __restrict__ next, int* __restrict__ colS,
                               int nE, int W) {
    int bucket = blockIdx.x & 7;
    int chunk  = blockIdx.x >> 3;
    int lo = bucket * W;
    int base = chunk * EPB;
    for (int k = threadIdx.x; k < EPB; k += 256) {
        int e = base + k;
        if (e < nE) {
            int r = __builtin_nontemporal_load(&row[e]);
            if ((unsigned)(r - lo) < (unsigned)W) {
                int c = __builtin_nontemporal_load(&col[e]);
                int pos = atomicAdd(&next[r], 1);
                colS[pos] = c;
            }
        }
    }
}

__global__ void scatter_iota(const int* __restrict__ idx, int* __restrict__ inext,
                             int* __restrict__ idxS, int n) {
    int j = blockIdx.x * blockDim.x + threadIdx.x;
    if (j < n) {
        int pos = atomicAdd(&inext[__builtin_nontemporal_load(&idx[j])], 1);
        idxS[pos] = j;
    }
}

// h0(bf16)[n] = x[n] + sum x_id[idxS[...]]  — 2 nodes/wave, 32 lanes/node
__global__ void init_plus_gather_bf(const int* __restrict__ iptr, const int* __restrict__ idxS,
                                    const float4* __restrict__ x, const float4* __restrict__ x_id,
                                    uint2* __restrict__ h, int n) {
    size_t tid = blockIdx.x * (size_t)blockDim.x + threadIdx.x;
    int wv   = (int)(tid >> 6);
    int lane = threadIdx.x & 63;
    int node = wv * 2 + (lane >> 5);
    int q    = lane & 31;
    if (node >= n) return;
    float4 a = x[(size_t)node * 32 + q];
    int e = iptr[node], end = iptr[node + 1];
    for (; e < end; ++e) {
        float4 v = x_id[(size_t)idxS[e] * 32 + q];
        a.x += v.x; a.y += v.y; a.z += v.z; a.w += v.w;
    }
    uint2 w;
    w.x = pack2(a.x, a.y);
    w.y = pack2(a.z, a.w);
    h[(size_t)node * 32 + q] = w;
}

// ---------------- hops: one wave per node, branch-free 32-edge body ----------------

#define CHUNK(K, A0,A1,A2,A3,A4,A5,A6,A7)                                             \
    {                                                                                 \
        int ee = e + 4 * K + g;                                                       \
        float m = (ee < end) ? 1.f : 0.f;                                             \
        if (ee >= end) ee = end - 1;                                                  \
        int c = __builtin_nontemporal_load(&colS[ee]);                                \
        uint4 v = h[(size_t)c * 16 + q];                                              \
        A0 += m * bflo(v.x); A1 += m * bfhi(v.x);                                     \
        A2 += m * bflo(v.y); A3 += m * bfhi(v.y);                                     \
        A4 += m * bflo(v.z); A5 += m * bfhi(v.z);                                     \
        A6 += m * bflo(v.w); A7 += m * bfhi(v.w);                                     \
    }

#define GATHER_BODY                                                                   \
    int wv = (int)((blockIdx.x * (size_t)blockDim.x + threadIdx.x) >> 6);             \
    if (wv >= n) return;                                                              \
    int lane = threadIdx.x & 63;                                                      \
    int g = lane >> 4;                                                                \
    int q = lane & 15;                                                                \
    int beg = ptr[wv], end = ptr[wv + 1];                                             \
    float a0 = 0, a1 = 0, a2 = 0, a3 = 0, a4 = 0, a5 = 0, a6 = 0, a7 = 0;             \
    float b0 = 0, b1 = 0, b2 = 0, b3 = 0, b4 = 0, b5 = 0, b6 = 0, b7 = 0;             \
    for (int e = beg; e < end; e += 32) {                                             \
        CHUNK(0, a0,a1,a2,a3,a4,a5,a6,a7)                                             \
        CHUNK(1, b0,b1,b2,b3,b4,b5,b6,b7)                                             \
        CHUNK(2, a0,a1,a2,a3,a4,a5,a6,a7)                                             \
        CHUNK(3, b0,b1,b2,b3,b4,b5,b6,b7)                                             \
        CHUNK(4, a0,a1,a2,a3,a4,a5,a6,a7)                                             \
        CHUNK(5, b0,b1,b2,b3,b4,b5,b6,b7)                                             \
        CHUNK(6, a0,a1,a2,a3,a4,a5,a6,a7)                                             \
        CHUNK(7, b0,b1,b2,b3,b4,b5,b6,b7)                                             \
    }                                                                                 \
    a0 += b0; a1 += b1; a2 += b2; a3 += b3;                                           \
    a4 += b4; a5 += b5; a6 += b6; a7 += b7;                                           \
    a0 += __shfl_xor(a0, 16, 64); a0 += __shfl_xor(a0, 32, 64);                       \
    a1 += __shfl_xor(a1, 16, 64); a1 += __shfl_xor(a1, 32, 64);                       \
    a2 += __shfl_xor(a2, 16, 64); a2 += __shfl_xor(a2, 32, 64);                       \
    a3 += __shfl_xor(a3, 16, 64); a3 += __shfl_xor(a3, 32, 64);                       \
    a4 += __shfl_xor(a4, 16, 64); a4 += __shfl_xor(a4, 32, 64);                       \
    a5 += __shfl_xor(a5, 16, 64); a5 += __shfl_xor(a5, 32, 64);                       \
    a6 += __shfl_xor(a6, 16, 64); a6 += __shfl_xor(a6, 32, 64);                       \
    a7 += __shfl_xor(a7, 16, 64); a7 += __shfl_xor(a7, 32, 64);

__global__ void gather_node_bf_bf(const int* __restrict__ ptr, const int* __restrict__ colS,
                                  const uint4* __restrict__ h, u32* __restrict__ out, int n) {
    GATHER_BODY
    if (g == 0) {
        u32x4 w;
        w.x = pack2(a0, a1);
        w.y = pack2(a2, a3);
        w.z = pack2(a4, a5);
        w.w = pack2(a6, a7);
        __builtin_nontemporal_store(w, (u32x4*)(out + (size_t)wv * 64 + q * 4));
    }
}

__global__ void gather_node_bf_f32(const int* __restrict__ ptr, const int* __restrict__ colS,
                                   const uint4* __restrict__ h, float* __restrict__ out, int n) {
    GATHER_BODY
    if (g == 0) {
        f32x4 w = {a0, a1, a2, a3};
        __builtin_nontemporal_store(w, (f32x4*)(out + (size_t)wv * 128 + q * 8));
    } else if (g == 1) {
        f32x4 w = {a4, a5, a6, a7};
        __builtin_nontemporal_store(w, (f32x4*)(out + (size_t)wv * 128 + q * 8 + 4));
    }
}

// ---------------- fallback kernels (atomic fp32 path) ----------------

__global__ void init_h0(const float4* __restrict__ x, float4* __restrict__ h, int n4) {
    int i = blockIdx.x * blockDim.x + threadIdx.x;
    if (i < n4) h[i] = x[i];
}

__global__ void scatter_id(const float4* __restrict__ x_id, const int* __restrict__ idx,
                           float* __restrict__ h, int n) {
    int t = blockIdx.x * blockDim.x + threadIdx.x;
    int r = t >> 5;
    int q = t & 31;
    if (r < n) {
        float4 v = x_id[r * 32 + q];
        float* o = h + (size_t)idx[r] * D_FEAT + q * 4;
        atomicAdd(o + 0, v.x);
        atomicAdd(o + 1, v.y);
        atomicAdd(o + 2, v.z);
        atomicAdd(o + 3, v.w);
    }
}

__global__ void edge_scatter(const int* __restrict__ row, const int* __restrict__ col,
                             const float4* __restrict__ h, float* __restrict__ out, int nE) {
    int t = blockIdx.x * blockDim.x + threadIdx.x;
    int e = t >> 5;
    int q = t & 31;
    if (e < nE) {
        float4 v = h[col[e] * 32 + q];
        float* o = out + (size_t)row[e] * D_FEAT + q * 4;
        atomicAdd(o + 0, v.x);
        atomicAdd(o + 1, v.y);
        atomicAdd(o + 2, v.z);
        atomicAdd(o + 3, v.w);
    }
}

extern "C" void kernel_launch(void* const* d_in, const int* in_sizes, int n_in,
                              void* d_out, int out_size, void* d_ws, size_t ws_size,
                              hipStream_t stream) {
    const float* x    = (const float*)d_in[0];
    const float* x_id = (const float*)d_in[1];
    const int*   edge = (const int*)d_in[2];   // [2, nE]: row then col
    const int*   idx  = (const int*)d_in[3];

    int nE = in_sizes[2] / 2;
    int nN = in_sizes[3];
    const int* row = edge;
    const int* col = edge + nE;

    float* out = (float*)d_out;
    size_t hbytes  = (size_t)nN * D_FEAT * sizeof(float);
    size_t hbbytes = (size_t)nN * D_FEAT * 2;
    int NB = (nN + 255) / 256;
    int W  = (nN + 7) / 8;

    // ---- workspace layout ----
    char* base = (char*)d_ws;
    uint4* hb0  = (uint4*)base;                            // hbbytes
    uint4* hb1  = (uint4*)(base + hbbytes);                // hbbytes
    int*   ptr   = (int*)(base + 2 * hbbytes);             // nN+1
    int*   next  = ptr + (nN + 1);                         // nN
    int*   bsum  = next + nN;                              // NB (padded)
    int*   colS  = bsum + ((NB + 3) & ~3);                 // nE
    int*   iptr  = colS + nE;                              // nN+1
    int*   inext = iptr + (nN + 1);                        // nN
    int*   ibsum = inext + nN;                             // NB (padded)
    int*   idxS  = ibsum + ((NB + 3) & ~3);                // nN
    u32*   cursor = (u32*)(idxS + nN);                     // 8 (pad 16)
    u32*   stag   = cursor + 16;                           // 8*capB
    int    capB   = nE / 8 + 16384;
    size_t needBF = 2 * hbbytes + sizeof(int) *
        ((size_t)(nN + 1) * 2 + (size_t)nN * 2 + 2 * ((NB + 3) & ~3) + nE + nN);
    size_t needST = needBF + sizeof(u32) * (16 + (size_t)capB * 8);

    int cbits = 0;
    while ((1 << cbits) < nN && cbits < 30) cbits++;
    int rbits = 0;
    while ((1 << rbits) < W && rbits < 30) rbits++;
    bool canPack = (cbits + rbits <= 32);

    int n4 = nN * D_FEAT / 4;
    unsigned int gEdge = (nE + 255) / 256;
    unsigned int gNode = (nN + 255) / 256;

    if (needBF > ws_size || NB > 1024) {
        float* h = (float*)d_ws;
        (void)hipMemsetAsync(out, 0, hbytes, stream);
        hipLaunchKernelGGL(init_h0, dim3((n4 + 255) / 256), dim3(256), 0, stream,
                           (const float4*)x, (float4*)h, n4);
        hipLaunchKernelGGL(scatter_id, dim3((nN * 32 + 255) / 256), dim3(256), 0, stream,
                           (const float4*)x_id, idx, h, nN);
        long long totE = (long long)nE * 32;
        unsigned int gE = (unsigned int)((totE + 255) / 256);
        hipLaunchKernelGGL(edge_scatter, dim3(gE), dim3(256), 0, stream,
                           row, col, (const float4*)h, out, nE);
        (void)hipMemsetAsync(h, 0, hbytes, stream);
        hipLaunchKernelGGL(edge_scatter, dim3(gE), dim3(256), 0, stream,
                           row, col, (const float4*)out, h, nE);
        (void)hipMemsetAsync(out, 0, hbytes, stream);
        hipLaunchKernelGGL(edge_scatter, dim3(gE), dim3(256), 0, stream,
                           row, col, (const float4*)h, out, nE);
        return;
    }

    bool useStaged = canPack && (needST <= ws_size);

    // ---- edge CSR build ----
    (void)hipMemsetAsync(next, 0, (size_t)nN * sizeof(int), stream);
    if (useStaged) {
        (void)hipMemsetAsync(cursor, 0, 16 * sizeof(u32), stream);
        u64 M = ((1ULL << 40) + W - 1) / (u64)W;
        unsigned int PB = (unsigned int)((nE + 4095) / 4096);
        hipLaunchKernelGGL(partition_ballot, dim3(PB), dim3(256), 0, stream,
                           row, col, next, cursor, stag, nE, W, M, cbits, capB);
        hipLaunchKernelGGL(scan_blocks, dim3(NB), dim3(256), 0, stream, next, ptr, bsum, nN);
        hipLaunchKernelGGL(scan_bsums, dim3(1), dim3(1024), 0, stream, bsum, NB);
        hipLaunchKernelGGL(add_offsets, dim3((nN + 1 + 255) / 256), dim3(256), 0, stream,
                           ptr, next, bsum, nN, nE);
        hipLaunchKernelGGL(scatter_staged, dim3(512), dim3(256), 0, stream,
                           cursor, stag, next, colS, W, cbits, capB);
    } else {
        hipLaunchKernelGGL(hist_keys, dim3(gEdge), dim3(256), 0, stream, row, next, nE);
        hipLaunchKernelGGL(scan_blocks, dim3(NB), dim3(256), 0, stream, next, ptr, bsum, nN);
        hipLaunchKernelGGL(scan_bsums, dim3(1), dim3(1024), 0, stream, bsum, NB);
        hipLaunchKernelGGL(add_offsets, dim3((nN + 1 + 255) / 256), dim3(256), 0, stream,
                           ptr, next, bsum, nN, nE);
        unsigned int nChunks = (nE + EPB - 1) / EPB;
        hipLaunchKernelGGL(scatter_cols_b, dim3(nChunks * 8), dim3(256), 0, stream,
                           row, col, next, colS, nE, W);
    }

    // ---- idx inversion + fused bf16 init ----
    (void)hipMemsetAsync(inext, 0, (size_t)nN * sizeof(int), stream);
    hipLaunchKernelGGL(hist_keys, dim3(gNode), dim3(256), 0, stream, idx, inext, nN);
    hipLaunchKernelGGL(scan_blocks, dim3(NB), dim3(256), 0, stream, inext, iptr, ibsum, nN);
    hipLaunchKernelGGL(scan_bsums, dim3(1), dim3(1024), 0, stream, ibsum, NB);
    hipLaunchKernelGGL(add_offsets, dim3((nN + 1 + 255) / 256), dim3(256), 0, stream,
                       iptr, inext, ibsum, nN, nN);
    hipLaunchKernelGGL(scatter_iota, dim3(gNode), dim3(256), 0, stream,
                       idx, inext, idxS, nN);

    unsigned int gI = (unsigned int)((((size_t)nN + 1) / 2 * 64 + 255) / 256);
    hipLaunchKernelGGL(init_plus_gather_bf, dim3(gI), dim3(256), 0, stream,
                       iptr, idxS, (const float4*)x, (const float4*)x_id, (uint2*)hb0, nN);

    // ---- hops: one wave per node ----
    unsigned int gW = (unsigned int)(((size_t)nN * 64 + 255) / 256);
    hipLaunchKernelGGL(gather_node_bf_bf, dim3(gW), dim3(256), 0, stream,
                       ptr, colS, (const uint4*)hb0, (u32*)hb1, nN);
    hipLaunchKernelGGL(gather_node_bf_bf, dim3(gW), dim3(256), 0, stream,
                       ptr, colS, (const uint4*)hb1, (u32*)hb0, nN);
    hipLaunchKernelGGL(gather_node_bf_f32, dim3(gW), dim3(256), 0, stream,
                       ptr, colS, (const uint4*)hb0, out, nN);
}

// Round 10
// 656.222 us; speedup vs baseline: 1.0120x; 1.0120x over previous
//
#include <hip/hip_runtime.h>

#define D_FEAT 128
typedef unsigned int u32;
typedef unsigned long long u64;
typedef u32   u32x4 __attribute__((ext_vector_type(4)));
typedef float f32x4 __attribute__((ext_vector_type(4)));

__device__ __forceinline__ float bflo(u32 w) {
    u32 b = w << 16;
    return __builtin_bit_cast(float, b);
}
__device__ __forceinline__ float bfhi(u32 w) {
    u32 b = w & 0xFFFF0000u;
    return __builtin_bit_cast(float, b);
}
__device__ __forceinline__ u32 f2bf(float f) {
    u32 x = __builtin_bit_cast(u32, f);
    return (x + 0x7FFFu + ((x >> 16) & 1u)) >> 16;
}
__device__ __forceinline__ u32 pack2(float lo, float hi) {
    return f2bf(lo) | (f2bf(hi) << 16);
}

// ---------------- CSR build helpers ----------------

__global__ void hist_keys(const int* __restrict__ key, int* __restrict__ deg, int n) {
    int e = blockIdx.x * blockDim.x + threadIdx.x;
    if (e < n) atomicAdd(&deg[__builtin_nontemporal_load(&key[e])], 1);
}

__global__ void scan_blocks(const int* __restrict__ deg, int* __restrict__ ptrOut,
                            int* __restrict__ bsum, int n) {
    __shared__ int s[256];
    int t = threadIdx.x;
    int i = blockIdx.x * 256 + t;
    int v = (i < n) ? deg[i] : 0;
    s[t] = v;
    __syncthreads();
    for (int off = 1; off < 256; off <<= 1) {
        int add = (t >= off) ? s[t - off] : 0;
        __syncthreads();
        s[t] += add;
        __syncthreads();
    }
    if (i < n) ptrOut[i] = s[t] - v;
    if (t == 255) bsum[blockIdx.x] = s[255];
}

__global__ void scan_bsums(int* __restrict__ bsum, int nb) {
    __shared__ int s[1024];
    int t = threadIdx.x;
    int v = (t < nb) ? bsum[t] : 0;
    s[t] = v;
    __syncthreads();
    for (int off = 1; off < 1024; off <<= 1) {
        int add = (t >= off) ? s[t - off] : 0;
        __syncthreads();
        s[t] += add;
        __syncthreads();
    }
    if (t < nb) bsum[t] = s[t] - v;
}

__global__ void add_offsets(int* __restrict__ ptr, int* __restrict__ next,
                            const int* __restrict__ bsum, int n, int total) {
    int i = blockIdx.x * blockDim.x + threadIdx.x;
    if (i < n) {
        int p = ptr[i] + bsum[i >> 8];
        ptr[i] = p;
        next[i] = p;
    }
    if (i == n) ptr[n] = total;
}

// ---- Phase A: ballot-aggregated partition into 8 staged buckets + deg hist ----
// 2048 edges/block (8/thread). Rank via 3 bitwise ballots; one cursor atomic
// per bucket per block; PLAIN staging stores (block-contiguous runs fill L2 lines).
__global__ void partition_ballot(const int* __restrict__ row, const int* __restrict__ col,
                                 int* __restrict__ deg, u32* __restrict__ cursor,
                                 u32* __restrict__ stag, int nE, int W,
                                 u64 M, int cbits, int capB) {
    __shared__ u32 wcnt[4][8];
    __shared__ u32 gwb[4][8];
    int t = threadIdx.x;
    int wv = t >> 6;
    int lane = t & 63;
    u64 ltmask = (1ull << lane) - 1;
    long long base = (long long)blockIdx.x * 2048;

    u32 cnt[8];
#pragma unroll
    for (int b = 0; b < 8; ++b) cnt[b] = 0;

    int bkt[8];
    int rk[8];
    u32 pk[8];

#pragma unroll
    for (int k = 0; k < 8; ++k) {
        long long e = base + k * 256 + t;
        bool val = e < nE;
        int r = 0, c = 0;
        if (val) {
            r = __builtin_nontemporal_load(&row[e]);
            c = __builtin_nontemporal_load(&col[e]);
            atomicAdd(&deg[r], 1);
        }
        int b = val ? (int)(((u64)(u32)r * M) >> 40) : 8;
        bkt[k] = b;
        pk[k] = ((u32)(r - b * W) << cbits) | (u32)c;
        u64 B0 = __ballot(val && (b & 1));
        u64 B1 = __ballot(val && (b & 2));
        u64 B2 = __ballot(val && (b & 4));
        u64 BV = __ballot(val);
#pragma unroll
        for (int bb = 0; bb < 8; ++bb) {
            u64 m = ((bb & 1) ? B0 : ~B0) & ((bb & 2) ? B1 : ~B1) &
                    ((bb & 4) ? B2 : ~B2) & BV;
            if (b == bb) rk[k] = (int)(cnt[bb] + (u32)__popcll(m & ltmask));
            cnt[bb] += (u32)__popcll(m);
        }
    }

    if (lane == 0) {
#pragma unroll
        for (int b = 0; b < 8; ++b) wcnt[wv][b] = cnt[b];
    }
    __syncthreads();
    if (t < 8) {
        u32 c0 = wcnt[0][t], c1 = wcnt[1][t], c2 = wcnt[2][t], c3 = wcnt[3][t];
        u32 gb = atomicAdd(&cursor[t], c0 + c1 + c2 + c3);
        gwb[0][t] = gb;
        gwb[1][t] = gb + c0;
        gwb[2][t] = gb + c0 + c1;
        gwb[3][t] = gb + c0 + c1 + c2;
    }
    __syncthreads();

#pragma unroll
    for (int k = 0; k < 8; ++k) {
        int b = bkt[k];
        if (b < 8) {
            u32 dst = gwb[wv][b] + (u32)rk[k];
            if (dst < (u32)capB)
                stag[(size_t)b * capB + dst] = pk[k];
        }
    }
}

// ---- Phase B: per-bucket atomic placement into its colS window (XCD affinity) ----
__global__ void scatter_staged(const u32* __restrict__ cursor, const u32* __restrict__ stag,
                               int* __restrict__ next, int* __restrict__ colS,
                               int W, int cbits, int capB) {
    int b = blockIdx.x & 7;
    int nchunk = gridDim.x >> 3;
    int chunk = blockIdx.x >> 3;
    int cnt = (int)cursor[b];
    if (cnt > capB) cnt = capB;
    int lo = b * W;
    u32 cmask = (1u << cbits) - 1;
    const u32* sb = stag + (size_t)b * capB;
    for (int i = chunk * 256 + threadIdx.x; i < cnt; i += nchunk * 256) {
        u32 w = __builtin_nontemporal_load(&sb[i]);
        int r = lo + (int)(w >> cbits);
        int c = (int)(w & cmask);
        int pos = atomicAdd(&next[r], 1);
        colS[pos] = c;
    }
}

// ---- fallback one-pass bucketed scatter (plain store) ----
#define EPB 2048
__global__ void scatter_cols_b(const int* __restrict__ row, const int* __restrict__ col,
                               int* __restrict__ next, int* __restrict__ colS,
                               int nE, int W) {
    int bucket = blockIdx.x & 7;
    int chunk  = blockIdx.x >> 3;
    int lo = bucket * W;
    int base = chunk * EPB;
    for (int k = threadIdx.x; k < EPB; k += 256) {
        int e = base + k;
        if (e < nE) {
            int r = __builtin_nontemporal_load(&row[e]);
            if ((unsigned)(r - lo) < (unsigned)W) {
                int c = __builtin_nontemporal_load(&col[e]);
                int pos = atomicAdd(&next[r], 1);
                colS[pos] = c;
            }
        }
    }
}

__global__ void scatter_iota(const int* __restrict__ idx, int* __restrict__ inext,
                             int* __restrict__ idxS, int n) {
    int j = blockIdx.x * blockDim.x + threadIdx.x;
    if (j < n) {
        int pos = atomicAdd(&inext[__builtin_nontemporal_load(&idx[j])], 1);
        idxS[pos] = j;
    }
}

// h0(bf16)[n] = x[n] + sum x_id[idxS[...]]  — 2 nodes/wave, 32 lanes/node
__global__ void init_plus_gather_bf(const int* __restrict__ iptr, const int* __restrict__ idxS,
                                    const float4* __restrict__ x, const float4* __restrict__ x_id,
                                    uint2* __restrict__ h, int n) {
    size_t tid = blockIdx.x * (size_t)blockDim.x + threadIdx.x;
    int wv   = (int)(tid >> 6);
    int lane = threadIdx.x & 63;
    int node = wv * 2 + (lane >> 5);
    int q    = lane & 31;
    if (node >= n) return;
    float4 a = x[(size_t)node * 32 + q];
    int e = iptr[node], end = iptr[node + 1];
    for (; e < end; ++e) {
        float4 v = x_id[(size_t)idxS[e] * 32 + q];
        a.x += v.x; a.y += v.y; a.z += v.z; a.w += v.w;
    }
    uint2 w;
    w.x = pack2(a.x, a.y);
    w.y = pack2(a.z, a.w);
    h[(size_t)node * 32 + q] = w;
}

// ---------------- hops: one wave per node, branch-free 32-edge body ----------------

#define CHUNK(K, A0,A1,A2,A3,A4,A5,A6,A7)                                             \
    {                                                                                 \
        int ee = e + 4 * K + g;                                                       \
        float m = (ee < end) ? 1.f : 0.f;                                             \
        if (ee >= end) ee = end - 1;                                                  \
        int c = __builtin_nontemporal_load(&colS[ee]);                                \
        uint4 v = h[(size_t)c * 16 + q];                                              \
        A0 += m * bflo(v.x); A1 += m * bfhi(v.x);                                     \
        A2 += m * bflo(v.y); A3 += m * bfhi(v.y);                                     \
        A4 += m * bflo(v.z); A5 += m * bfhi(v.z);                                     \
        A6 += m * bflo(v.w); A7 += m * bfhi(v.w);                                     \
    }

#define GATHER_BODY                                                                   \
    int wv = (int)((blockIdx.x * (size_t)blockDim.x + threadIdx.x) >> 6);             \
    if (wv >= n) return;                                                              \
    int lane = threadIdx.x & 63;                                                      \
    int g = lane >> 4;                                                                \
    int q = lane & 15;                                                                \
    int beg = ptr[wv], end = ptr[wv + 1];                                             \
    float a0 = 0, a1 = 0, a2 = 0, a3 = 0, a4 = 0, a5 = 0, a6 = 0, a7 = 0;             \
    float b0 = 0, b1 = 0, b2 = 0, b3 = 0, b4 = 0, b5 = 0, b6 = 0, b7 = 0;             \
    for (int e = beg; e < end; e += 32) {                                             \
        CHUNK(0, a0,a1,a2,a3,a4,a5,a6,a7)                                             \
        CHUNK(1, b0,b1,b2,b3,b4,b5,b6,b7)                                             \
        CHUNK(2, a0,a1,a2,a3,a4,a5,a6,a7)                                             \
        CHUNK(3, b0,b1,b2,b3,b4,b5,b6,b7)                                             \
        CHUNK(4, a0,a1,a2,a3,a4,a5,a6,a7)                                             \
        CHUNK(5, b0,b1,b2,b3,b4,b5,b6,b7)                                             \
        CHUNK(6, a0,a1,a2,a3,a4,a5,a6,a7)                                             \
        CHUNK(7, b0,b1,b2,b3,b4,b5,b6,b7)                                             \
    }                                                                                 \
    a0 += b0; a1 += b1; a2 += b2; a3 += b3;                                           \
    a4 += b4; a5 += b5; a6 += b6; a7 += b7;                                           \
    a0 += __shfl_xor(a0, 16, 64); a0 += __shfl_xor(a0, 32, 64);                       \
    a1 += __shfl_xor(a1, 16, 64); a1 += __shfl_xor(a1, 32, 64);                       \
    a2 += __shfl_xor(a2, 16, 64); a2 += __shfl_xor(a2, 32, 64);                       \
    a3 += __shfl_xor(a3, 16, 64); a3 += __shfl_xor(a3, 32, 64);                       \
    a4 += __shfl_xor(a4, 16, 64); a4 += __shfl_xor(a4, 32, 64);                       \
    a5 += __shfl_xor(a5, 16, 64); a5 += __shfl_xor(a5, 32, 64);                       \
    a6 += __shfl_xor(a6, 16, 64); a6 += __shfl_xor(a6, 32, 64);                       \
    a7 += __shfl_xor(a7, 16, 64); a7 += __shfl_xor(a7, 32, 64);

__global__ void gather_node_bf_bf(const int* __restrict__ ptr, const int* __restrict__ colS,
                                  const uint4* __restrict__ h, u32* __restrict__ out, int n) {
    GATHER_BODY
    if (g == 0) {
        u32x4 w;
        w.x = pack2(a0, a1);
        w.y = pack2(a2, a3);
        w.z = pack2(a4, a5);
        w.w = pack2(a6, a7);
        __builtin_nontemporal_store(w, (u32x4*)(out + (size_t)wv * 64 + q * 4));
    }
}

__global__ void gather_node_bf_f32(const int* __restrict__ ptr, const int* __restrict__ colS,
                                   const uint4* __restrict__ h, float* __restrict__ out, int n) {
    GATHER_BODY
    if (g == 0) {
        f32x4 w = {a0, a1, a2, a3};
        __builtin_nontemporal_store(w, (f32x4*)(out + (size_t)wv * 128 + q * 8));
    } else if (g == 1) {
        f32x4 w = {a4, a5, a6, a7};
        __builtin_nontemporal_store(w, (f32x4*)(out + (size_t)wv * 128 + q * 8 + 4));
    }
}

// ---------------- fallback kernels (atomic fp32 path) ----------------

__global__ void init_h0(const float4* __restrict__ x, float4* __restrict__ h, int n4) {
    int i = blockIdx.x * blockDim.x + threadIdx.x;
    if (i < n4) h[i] = x[i];
}

__global__ void scatter_id(const float4* __restrict__ x_id, const int* __restrict__ idx,
                           float* __restrict__ h, int n) {
    int t = blockIdx.x * blockDim.x + threadIdx.x;
    int r = t >> 5;
    int q = t & 31;
    if (r < n) {
        float4 v = x_id[r * 32 + q];
        float* o = h + (size_t)idx[r] * D_FEAT + q * 4;
        atomicAdd(o + 0, v.x);
        atomicAdd(o + 1, v.y);
        atomicAdd(o + 2, v.z);
        atomicAdd(o + 3, v.w);
    }
}

__global__ void edge_scatter(const int* __restrict__ row, const int* __restrict__ col,
                             const float4* __restrict__ h, float* __restrict__ out, int nE) {
    int t = blockIdx.x * blockDim.x + threadIdx.x;
    int e = t >> 5;
    int q = t & 31;
    if (e < nE) {
        float4 v = h[col[e] * 32 + q];
        float* o = out + (size_t)row[e] * D_FEAT + q * 4;
        atomicAdd(o + 0, v.x);
        atomicAdd(o + 1, v.y);
        atomicAdd(o + 2, v.z);
        atomicAdd(o + 3, v.w);
    }
}

extern "C" void kernel_launch(void* const* d_in, const int* in_sizes, int n_in,
                              void* d_out, int out_size, void* d_ws, size_t ws_size,
                              hipStream_t stream) {
    const float* x    = (const float*)d_in[0];
    const float* x_id = (const float*)d_in[1];
    const int*   edge = (const int*)d_in[2];   // [2, nE]: row then col
    const int*   idx  = (const int*)d_in[3];

    int nE = in_sizes[2] / 2;
    int nN = in_sizes[3];
    const int* row = edge;
    const int* col = edge + nE;

    float* out = (float*)d_out;
    size_t hbytes  = (size_t)nN * D_FEAT * sizeof(float);
    size_t hbbytes = (size_t)nN * D_FEAT * 2;
    int NB = (nN + 255) / 256;
    int W  = (nN + 7) / 8;

    // ---- workspace layout ----
    char* base = (char*)d_ws;
    uint4* hb0  = (uint4*)base;                            // hbbytes
    uint4* hb1  = (uint4*)(base + hbbytes);                // hbbytes
    int*   ptr   = (int*)(base + 2 * hbbytes);             // nN+1
    int*   next  = ptr + (nN + 1);                         // nN
    int*   bsum  = next + nN;                              // NB (padded)
    int*   colS  = bsum + ((NB + 3) & ~3);                 // nE
    int*   iptr  = colS + nE;                              // nN+1
    int*   inext = iptr + (nN + 1);                        // nN
    int*   ibsum = inext + nN;                             // NB (padded)
    int*   idxS  = ibsum + ((NB + 3) & ~3);                // nN
    u32*   cursor = (u32*)(idxS + nN);                     // 8 (pad 16)
    u32*   stag   = cursor + 16;                           // 8*capB
    int    capB   = nE / 8 + 16384;
    size_t needBF = 2 * hbbytes + sizeof(int) *
        ((size_t)(nN + 1) * 2 + (size_t)nN * 2 + 2 * ((NB + 3) & ~3) + nE + nN);
    size_t needST = needBF + sizeof(u32) * (16 + (size_t)capB * 8);

    int cbits = 0;
    while ((1 << cbits) < nN && cbits < 30) cbits++;
    int rbits = 0;
    while ((1 << rbits) < W && rbits < 30) rbits++;
    bool canPack = (cbits + rbits <= 32);

    int n4 = nN * D_FEAT / 4;
    unsigned int gEdge = (nE + 255) / 256;
    unsigned int gNode = (nN + 255) / 256;

    if (needBF > ws_size || NB > 1024) {
        float* h = (float*)d_ws;
        (void)hipMemsetAsync(out, 0, hbytes, stream);
        hipLaunchKernelGGL(init_h0, dim3((n4 + 255) / 256), dim3(256), 0, stream,
                           (const float4*)x, (float4*)h, n4);
        hipLaunchKernelGGL(scatter_id, dim3((nN * 32 + 255) / 256), dim3(256), 0, stream,
                           (const float4*)x_id, idx, h, nN);
        long long totE = (long long)nE * 32;
        unsigned int gE = (unsigned int)((totE + 255) / 256);
        hipLaunchKernelGGL(edge_scatter, dim3(gE), dim3(256), 0, stream,
                           row, col, (const float4*)h, out, nE);
        (void)hipMemsetAsync(h, 0, hbytes, stream);
        hipLaunchKernelGGL(edge_scatter, dim3(gE), dim3(256), 0, stream,
                           row, col, (const float4*)out, h, nE);
        (void)hipMemsetAsync(out, 0, hbytes, stream);
        hipLaunchKernelGGL(edge_scatter, dim3(gE), dim3(256), 0, stream,
                           row, col, (const float4*)h, out, nE);
        return;
    }

    bool useStaged = canPack && (needST <= ws_size);

    // ---- edge CSR build ----
    (void)hipMemsetAsync(next, 0, (size_t)nN * sizeof(int), stream);
    if (useStaged) {
        (void)hipMemsetAsync(cursor, 0, 16 * sizeof(u32), stream);
        u64 M = ((1ULL << 40) + W - 1) / (u64)W;
        unsigned int PB = (unsigned int)((nE + 2047) / 2048);
        hipLaunchKernelGGL(partition_ballot, dim3(PB), dim3(256), 0, stream,
                           row, col, next, cursor, stag, nE, W, M, cbits, capB);
        hipLaunchKernelGGL(scan_blocks, dim3(NB), dim3(256), 0, stream, next, ptr, bsum, nN);
        hipLaunchKernelGGL(scan_bsums, dim3(1), dim3(1024), 0, stream, bsum, NB);
        hipLaunchKernelGGL(add_offsets, dim3((nN + 1 + 255) / 256), dim3(256), 0, stream,
                           ptr, next, bsum, nN, nE);
        hipLaunchKernelGGL(scatter_staged, dim3(512), dim3(256), 0, stream,
                           cursor, stag, next, colS, W, cbits, capB);
    } else {
        hipLaunchKernelGGL(hist_keys, dim3(gEdge), dim3(256), 0, stream, row, next, nE);
        hipLaunchKernelGGL(scan_blocks, dim3(NB), dim3(256), 0, stream, next, ptr, bsum, nN);
        hipLaunchKernelGGL(scan_bsums, dim3(1), dim3(1024), 0, stream, bsum, NB);
        hipLaunchKernelGGL(add_offsets, dim3((nN + 1 + 255) / 256), dim3(256), 0, stream,
                           ptr, next, bsum, nN, nE);
        unsigned int nChunks = (nE + EPB - 1) / EPB;
        hipLaunchKernelGGL(scatter_cols_b, dim3(nChunks * 8), dim3(256), 0, stream,
                           row, col, next, colS, nE, W);
    }

    // ---- idx inversion + fused bf16 init ----
    (void)hipMemsetAsync(inext, 0, (size_t)nN * sizeof(int), stream);
    hipLaunchKernelGGL(hist_keys, dim3(gNode), dim3(256), 0, stream, idx, inext, nN);
    hipLaunchKernelGGL(scan_blocks, dim3(NB), dim3(256), 0, stream, inext, iptr, ibsum, nN);
    hipLaunchKernelGGL(scan_bsums, dim3(1), dim3(1024), 0, stream, ibsum, NB);
    hipLaunchKernelGGL(add_offsets, dim3((nN + 1 + 255) / 256), dim3(256), 0, stream,
                       iptr, inext, ibsum, nN, nN);
    hipLaunchKernelGGL(scatter_iota, dim3(gNode), dim3(256), 0, stream,
                       idx, inext, idxS, nN);

    unsigned int gI = (unsigned int)((((size_t)nN + 1) / 2 * 64 + 255) / 256);
    hipLaunchKernelGGL(init_plus_gather_bf, dim3(gI), dim3(256), 0, stream,
                       iptr, idxS, (const float4*)x, (const float4*)x_id, (uint2*)hb0, nN);

    // ---- hops: one wave per node ----
    unsigned int gW = (unsigned int)(((size_t)nN * 64 + 255) / 256);
    hipLaunchKernelGGL(gather_node_bf_bf, dim3(gW), dim3(256), 0, stream,
                       ptr, colS, (const uint4*)hb0, (u32*)hb1, nN);
    hipLaunchKernelGGL(gather_node_bf_bf, dim3(gW), dim3(256), 0, stream,
                       ptr, colS, (const uint4*)hb1, (u32*)hb0, nN);
    hipLaunchKernelGGL(gather_node_bf_f32, dim3(gW), dim3(256), 0, stream,
                       ptr, colS, (const uint4*)hb0, out, nN);
}